// Round 17
// baseline (779.386 us; speedup 1.0000x reference)
//
#include <hip/hip_runtime.h>

constexpr int Bc = 32, Tc = 2048, Hc = 512;

typedef _Float16 f16;
typedef _Float16 f16x8 __attribute__((ext_vector_type(8)));
typedef float f32x4 __attribute__((ext_vector_type(4)));

__device__ __forceinline__ void gload_lds16(const void* g, void* l) {
  __builtin_amdgcn_global_load_lds(
      (const __attribute__((address_space(1))) void*)g,
      (__attribute__((address_space(3))) void*)l, 16, 0, 0);
}

// hardware-exp math: v_exp_f32 is 2^x, ~1 ulp
__device__ __forceinline__ float fast_exp(float x) {
  return __builtin_amdgcn_exp2f(x * 1.4426950408889634f);
}
__device__ __forceinline__ float fast_tanh(float x) {
  const float z = __builtin_amdgcn_exp2f(x * 2.8853900817779268f);  // e^(2x)
  return (z - 1.0f) * __builtin_amdgcn_rcpf(z + 1.0f);
}

// ---------- transpose + f32->f16 convert for x/t: [b][t][h] -> [b][h][t] ----------
__global__ __launch_bounds__(256) void cvt_bth(const float* __restrict__ xin,
                                               const float* __restrict__ tin,
                                               f16* __restrict__ xo,
                                               f16* __restrict__ to) {
  __shared__ f16 tile[64][65];
  const int tid = threadIdx.x;
  const int t0 = blockIdx.x * 64, h0 = blockIdx.y * 64;
  int z = blockIdx.z;
  const float* src;
  f16* dst;
  if (z < Bc) { src = xin; dst = xo; } else { src = tin; dst = to; z -= Bc; }
  src += (size_t)z * Tc * Hc;
  dst += (size_t)z * Hc * Tc;
  const int c4 = tid & 15, r0 = tid >> 4;
#pragma unroll
  for (int rr = 0; rr < 64; rr += 16) {
    const float4 v = *(const float4*)(src + (size_t)(t0 + rr + r0) * Hc + h0 + c4 * 4);
    tile[rr + r0][c4 * 4 + 0] = (f16)v.x;
    tile[rr + r0][c4 * 4 + 1] = (f16)v.y;
    tile[rr + r0][c4 * 4 + 2] = (f16)v.z;
    tile[rr + r0][c4 * 4 + 3] = (f16)v.w;
  }
  __syncthreads();
  const int tc = tid & 7, hr = tid >> 3;
#pragma unroll
  for (int hp = 0; hp < 64; hp += 32) {
    const int h = hp + hr;
    f16x8 o;
#pragma unroll
    for (int j = 0; j < 8; ++j) o[j] = tile[tc * 8 + j][h];
    *(f16x8*)(dst + (size_t)(h0 + h) * Tc + t0 + tc * 8) = o;
  }
}

// ---------- transpose + convert for the three TxT kernels: [t][s] -> [s][t] ----------
__global__ __launch_bounds__(256) void cvt_tt(const float* __restrict__ kx,
                                              const float* __restrict__ kt,
                                              const float* __restrict__ ka,
                                              f16* __restrict__ ox,
                                              f16* __restrict__ ot,
                                              f16* __restrict__ oa) {
  __shared__ f16 tile[64][65];
  const int tid = threadIdx.x;
  const int t0 = blockIdx.x * 64, s0 = blockIdx.y * 64;
  const float* src = blockIdx.z == 0 ? kx : (blockIdx.z == 1 ? kt : ka);
  f16* dst = blockIdx.z == 0 ? ox : (blockIdx.z == 1 ? ot : oa);
  const int c4 = tid & 15, r0 = tid >> 4;
#pragma unroll
  for (int rr = 0; rr < 64; rr += 16) {
    const float4 v = *(const float4*)(src + (size_t)(t0 + rr + r0) * Tc + s0 + c4 * 4);
    tile[rr + r0][c4 * 4 + 0] = (f16)v.x;
    tile[rr + r0][c4 * 4 + 1] = (f16)v.y;
    tile[rr + r0][c4 * 4 + 2] = (f16)v.z;
    tile[rr + r0][c4 * 4 + 3] = (f16)v.w;
  }
  __syncthreads();
  const int tc = tid & 7, sr = tid >> 3;
#pragma unroll
  for (int sp = 0; sp < 64; sp += 32) {
    const int s = sp + sr;
    f16x8 o;
#pragma unroll
    for (int j = 0; j < 8; ++j) o[j] = tile[tc * 8 + j][s];
    *(f16x8*)(dst + (size_t)(s0 + s) * Tc + t0 + tc * 8) = o;
  }
}

// ---------- 256x256 GEMM: A via LDS, B DIRECT global->register ----------
// Diagnosis R15: kernel was at the LDS-port roofline (ds_read 2304cy + staging
// 512cy > MFMA 2048cy per K64). Fix: B-fragments load straight from L2 into
// registers (1-tile-ahead double buffer) -> LDS traffic drops ~2.1x; port
// (~896cy/K32) < MFMA (1024cy/K32).
// BK=32, A-only LDS: 3 buffers x 16 KiB, stage-ahead-2, 1 barrier/tile.
// vmcnt ledger (order pinned by sched_barrier between B-loads and A-stages):
//   steady issue/tile = B(t+1)x4, A(t+2)x2; vmcnt(8) pre-MFMA (B(t) landed),
//   vmcnt(6) pre-barrier (A(t+1) landed); tails 6/4 then 0.
template <int MODE>
__global__ __launch_bounds__(512, 2) void gemm_k(const f16* __restrict__ A,
                                                 const f16* __restrict__ Bm,
                                                 void* __restrict__ Cout,
                                                 const f16* __restrict__ Gprev,
                                                 const float* __restrict__ bias,
                                                 const float* __restrict__ lambd,
                                                 float* __restrict__ psums) {
  extern __shared__ char smem[];
  constexpr int BK = 32, NT = Tc / BK;            // 64 K-tiles
  constexpr int ABUF = 16384;                     // 256 rows x 64B per buffer
  const int tid = threadIdx.x;
  const int lane = tid & 63, w = tid >> 6;
  const int wr = w >> 2, wc = w & 3;              // 2 x 4 wave grid
  const int l15 = lane & 15, kg = lane >> 4;

  // grid: 512 blocks, XCD-bijective swizzle (512 % 8 == 0)
  int id = (int)blockIdx.x;
  id = (id & 7) * ((int)gridDim.x >> 3) + (id >> 3);
  int b, m0, n0;
  if constexpr (MODE == 2) {
    b = id >> 4; m0 = ((id >> 1) & 7) * 256; n0 = (id & 1) * 256;
  } else {
    b = 0; m0 = (id >> 3) * 256; n0 = (id & 7) * 256;
  }

  const size_t K = Tc;
  const size_t HT = (size_t)Hc * Tc;
  const f16* Ag = A + (size_t)m0 * K;
  const f16* Bg = Bm + (MODE == 2 ? (size_t)b * HT : (size_t)0) + (size_t)n0 * K;

  // A staging (proven swizzle pair): wave w stages rows w*32..w*32+31 (2 gloads)
  const int r4 = lane >> 2;
  const int cswz = ((lane & 3) ^ ((lane >> 3) & 3)) * 8;
  const f16* gAs = Ag + (size_t)(w * 32 + r4) * K + cswz;
  const int ldsW = w * 2048;

  // A fragment read base (proven zero-conflict): + i*1024, i<8
  const int chunk16 = (kg ^ ((l15 >> 1) & 3)) * 16;
  const int aoff = (wr * 128 + l15) * 64 + chunk16;

  // B direct-load row base (per j: +j*16 rows); per-lane 16B at k = t*32 + kg*8
  const f16* Bl = Bg + (size_t)(wc * 64 + l15) * K + kg * 8;

  f32x4 acc[8][4];
#pragma unroll
  for (int i = 0; i < 8; ++i)
#pragma unroll
    for (int j = 0; j < 4; ++j) acc[i][j] = {0.f, 0.f, 0.f, 0.f};

  f16x8 bcE[4], bcO[4], af[8];

#define LOADB(DST, T) do {                                                   \
    _Pragma("unroll")                                                        \
    for (int j = 0; j < 4; ++j)                                              \
      DST[j] = *(const f16x8*)(Bl + (size_t)(j * 16) * K + (size_t)(T) * 32);} while (0)

#define STGA(T) do {                                                         \
    char* dA = smem + ((T) % 3) * ABUF + ldsW;                               \
    gload_lds16(gAs + (size_t)(T) * BK, dA);                                 \
    gload_lds16(gAs + (size_t)16 * K + (size_t)(T) * BK, dA + 1024); } while (0)

#define MFMA_(a, bq, d) d = __builtin_amdgcn_mfma_f32_16x16x32_f16(a, bq, d, 0, 0, 0)
#define SB __builtin_amdgcn_sched_barrier(0)
#define BAR __builtin_amdgcn_s_barrier()
#define SP1 __builtin_amdgcn_s_setprio(1)
#define SP0 __builtin_amdgcn_s_setprio(0)

  // prologue: B(0) -> bcE; stage A(0), A(1)
  LOADB(bcE, 0);
  SB;
  STGA(0);
  STGA(1);
  SB;
  asm volatile("s_waitcnt vmcnt(2)");  // B(0), A(0) landed; A(1) in flight
  BAR;
  SB;

#define TILE(T, BCC, BCN) do {                                               \
    const char* bufc = smem + ((T) % 3) * ABUF;                              \
    _Pragma("unroll")                                                        \
    for (int i = 0; i < 8; ++i) af[i] = *(const f16x8*)(bufc + aoff + i * 1024); \
    if ((T) + 1 < NT) LOADB(BCN, (T) + 1);                                   \
    SB;                                                                      \
    if ((T) + 2 < NT) STGA((T) + 2);                                         \
    SB;                                                                      \
    if ((T) < NT - 2)       { asm volatile("s_waitcnt vmcnt(8)"); }          \
    else if ((T) == NT - 2) { asm volatile("s_waitcnt vmcnt(6)"); }          \
    else                    { asm volatile("s_waitcnt vmcnt(0)"); }          \
    SP1;                                                                     \
    _Pragma("unroll")                                                        \
    for (int i = 0; i < 4; ++i)                                              \
      _Pragma("unroll")                                                      \
      for (int j = 0; j < 4; ++j) MFMA_(af[i], BCC[j], acc[i][j]);           \
    SP0;                                                                     \
    if ((T) < NT - 2)       { asm volatile("s_waitcnt vmcnt(6)"); }          \
    else if ((T) == NT - 2) { asm volatile("s_waitcnt vmcnt(4)"); }          \
    asm volatile("s_waitcnt lgkmcnt(0)");                                    \
    BAR;                                                                     \
    SB;                                                                      \
    SP1;                                                                     \
    _Pragma("unroll")                                                        \
    for (int i = 0; i < 4; ++i)                                              \
      _Pragma("unroll")                                                      \
      for (int j = 0; j < 4; ++j) MFMA_(af[4 + i], BCC[j], acc[4 + i][j]);   \
    SP0;                                                                     \
  } while (0)

  for (int t = 0; t < NT; t += 2) {
    TILE(t, bcE, bcO);
    TILE(t + 1, bcO, bcE);
  }

  // ---- epilogue (hardware-exp transcendentals) ----
  float psum[4] = {0.f, 0.f, 0.f, 0.f};
#pragma unroll
  for (int i = 0; i < 8; ++i) {
#pragma unroll
    for (int r = 0; r < 4; ++r) {
      const int gr = m0 + wr * 128 + i * 16 + kg * 4 + r;
#pragma unroll
      for (int j = 0; j < 4; ++j) {
        const int gc = n0 + wc * 64 + j * 16 + l15;
        const float v = acc[i][j][r];
        if constexpr (MODE == 0) {
          f16* C = (f16*)Cout;
          C[(size_t)gr * Tc + gc] = (f16)fast_tanh(v + bias[gc]);
        } else if constexpr (MODE == 1) {
          f16* C = (f16*)Cout;
          const size_t idx = (size_t)gr * Tc + gc;
          const float g = (float)Gprev[idx];
          const float lam = lambd[gr & 511];
          C[idx] = (f16)(lam * g + (1.f - lam) * fast_tanh(v + bias[gc]));
        } else {
          // no-max softmax numerator: logits O(1); shift-invariant vs reference.
          f16* Es = (f16*)Cout;
          const float e = fast_exp(v);
          Es[((size_t)b * Tc + gr) * Hc + gc] = (f16)e;
          psum[j] += e;
        }
      }
    }
  }
  if constexpr (MODE == 2) {
    float* ps = (float*)smem;
    __syncthreads();
#pragma unroll
    for (int j = 0; j < 4; ++j)
      ps[(wr * 4 + kg) * 256 + (wc * 64 + j * 16 + l15)] = psum[j];
    __syncthreads();
    if (tid < 256) {
      float s = 0.f;
#pragma unroll
      for (int p = 0; p < 8; ++p) s += ps[p * 256 + tid];
      psums[((size_t)b * 8 + (m0 >> 8)) * Hc + n0 + tid] = s;
    }
  }
}

// ---------- normalize: out[b][s'][h] = Es[b][s'][h] / sum_p psums[b][p][h] ----------
__global__ __launch_bounds__(1024) void norm_k(const f16* __restrict__ Es,
                                               const float* __restrict__ psums,
                                               float* __restrict__ out) {
  __shared__ float inv[512];
  const int tid = threadIdx.x;
  const int b = blockIdx.x >> 4, sseg = blockIdx.x & 15;
  if (tid < 512) {
    float s = 0.f;
    const float* P = psums + (size_t)b * 8 * Hc + tid;
#pragma unroll
    for (int p = 0; p < 8; ++p) s += P[p * Hc];
    inv[tid] = 1.f / s;
  }
  __syncthreads();
  const int hg = (tid & 63) * 8;
  const int so = tid >> 6;
  float iv[8];
#pragma unroll
  for (int j = 0; j < 8; ++j) iv[j] = inv[hg + j];
  const size_t base = ((size_t)b * Tc + sseg * 128) * Hc;
  for (int r = so; r < 128; r += 16) {
    const size_t idx = base + (size_t)r * Hc + hg;
    const f16x8 e = *(const f16x8*)(Es + idx);
    float4 o0, o1;
    o0.x = (float)e[0] * iv[0]; o0.y = (float)e[1] * iv[1];
    o0.z = (float)e[2] * iv[2]; o0.w = (float)e[3] * iv[3];
    o1.x = (float)e[4] * iv[4]; o1.y = (float)e[5] * iv[5];
    o1.z = (float)e[6] * iv[6]; o1.w = (float)e[7] * iv[7];
    *(float4*)(out + idx) = o0;
    *(float4*)(out + idx + 4) = o1;
  }
}

extern "C" void kernel_launch(void* const* d_in, const int* in_sizes, int n_in,
                              void* d_out, int out_size, void* d_ws, size_t ws_size,
                              hipStream_t stream) {
  const float* x  = (const float*)d_in[0];
  const float* tt = (const float*)d_in[1];
  const float* kx = (const float*)d_in[2];
  const float* kt = (const float*)d_in[3];
  const float* ka = (const float*)d_in[4];
  const float* bx = (const float*)d_in[5];
  const float* bt = (const float*)d_in[6];
  const float* lm = (const float*)d_in[7];
  float* out = (float*)d_out;

  const size_t NBHT = (size_t)Bc * Hc * Tc;  // 33,554,432 elements

  // d_out doubles as scratch for the f16-transposed inputs until norm_k overwrites it
  f16* XhT = (f16*)d_out;
  f16* ThT = XhT + NBHT;

  // workspace: Gt(64MiB) Dt(64MiB) KxT(8) KtT(8) KaT(8)
  f16* Gt  = (f16*)d_ws;
  f16* Dt  = Gt + NBHT;
  f16* KxT = Dt + NBHT;
  f16* KtT = KxT + (size_t)Tc * Tc;
  f16* KaT = KtT + (size_t)Tc * Tc;
  float* Ps = (float*)KxT;   // psums reuses KxT (dead after gemm_k<0>)
  f16* Es = Gt;              // exp numerators reuse Gt (dead after gemm_k<1>)

  constexpr int LDS_BYTES = 3 * 16384;  // 49152: A-only triple buffer
  (void)hipFuncSetAttribute(reinterpret_cast<const void*>(gemm_k<0>),
                            hipFuncAttributeMaxDynamicSharedMemorySize, LDS_BYTES);
  (void)hipFuncSetAttribute(reinterpret_cast<const void*>(gemm_k<1>),
                            hipFuncAttributeMaxDynamicSharedMemorySize, LDS_BYTES);
  (void)hipFuncSetAttribute(reinterpret_cast<const void*>(gemm_k<2>),
                            hipFuncAttributeMaxDynamicSharedMemorySize, LDS_BYTES);

  cvt_bth<<<dim3(Tc / 64, Hc / 64, Bc * 2), 256, 0, stream>>>(x, tt, XhT, ThT);
  cvt_tt<<<dim3(Tc / 64, Tc / 64, 3), 256, 0, stream>>>(kx, kt, ka, KxT, KtT, KaT);
  gemm_k<0><<<512, 512, LDS_BYTES, stream>>>(XhT, KxT, Gt, nullptr, bx, nullptr, nullptr);
  gemm_k<1><<<512, 512, LDS_BYTES, stream>>>(ThT, KtT, Dt, Gt, bt, lm, nullptr);
  gemm_k<2><<<512, 512, LDS_BYTES, stream>>>(KaT, Dt, Es, nullptr, nullptr, nullptr, Ps);
  norm_k<<<dim3(Bc * 16), 1024, 0, stream>>>(Es, Ps, out);
}

// Round 18
// 515.354 us; speedup vs baseline: 1.5123x; 1.5123x over previous
//
#include <hip/hip_runtime.h>

constexpr int Bc = 32, Tc = 2048, Hc = 512;

typedef _Float16 f16;
typedef _Float16 f16x8 __attribute__((ext_vector_type(8)));
typedef float f32x4 __attribute__((ext_vector_type(4)));

__device__ __forceinline__ void gload_lds16(const void* g, void* l) {
  __builtin_amdgcn_global_load_lds(
      (const __attribute__((address_space(1))) void*)g,
      (__attribute__((address_space(3))) void*)l, 16, 0, 0);
}

// hardware-exp math: v_exp_f32 is 2^x, ~1 ulp
__device__ __forceinline__ float fast_exp(float x) {
  return __builtin_amdgcn_exp2f(x * 1.4426950408889634f);
}
__device__ __forceinline__ float fast_tanh(float x) {
  const float z = __builtin_amdgcn_exp2f(x * 2.8853900817779268f);  // e^(2x)
  return (z - 1.0f) * __builtin_amdgcn_rcpf(z + 1.0f);
}

// ---------- transpose + f32->f16 convert for x/t: [b][t][h] -> [b][h][t] ----------
__global__ __launch_bounds__(256) void cvt_bth(const float* __restrict__ xin,
                                               const float* __restrict__ tin,
                                               f16* __restrict__ xo,
                                               f16* __restrict__ to) {
  __shared__ f16 tile[64][65];
  const int tid = threadIdx.x;
  const int t0 = blockIdx.x * 64, h0 = blockIdx.y * 64;
  int z = blockIdx.z;
  const float* src;
  f16* dst;
  if (z < Bc) { src = xin; dst = xo; } else { src = tin; dst = to; z -= Bc; }
  src += (size_t)z * Tc * Hc;
  dst += (size_t)z * Hc * Tc;
  const int c4 = tid & 15, r0 = tid >> 4;
#pragma unroll
  for (int rr = 0; rr < 64; rr += 16) {
    const float4 v = *(const float4*)(src + (size_t)(t0 + rr + r0) * Hc + h0 + c4 * 4);
    tile[rr + r0][c4 * 4 + 0] = (f16)v.x;
    tile[rr + r0][c4 * 4 + 1] = (f16)v.y;
    tile[rr + r0][c4 * 4 + 2] = (f16)v.z;
    tile[rr + r0][c4 * 4 + 3] = (f16)v.w;
  }
  __syncthreads();
  const int tc = tid & 7, hr = tid >> 3;
#pragma unroll
  for (int hp = 0; hp < 64; hp += 32) {
    const int h = hp + hr;
    f16x8 o;
#pragma unroll
    for (int j = 0; j < 8; ++j) o[j] = tile[tc * 8 + j][h];
    *(f16x8*)(dst + (size_t)(h0 + h) * Tc + t0 + tc * 8) = o;
  }
}

// ---------- transpose + convert for the three TxT kernels: [t][s] -> [s][t] ----------
__global__ __launch_bounds__(256) void cvt_tt(const float* __restrict__ kx,
                                              const float* __restrict__ kt,
                                              const float* __restrict__ ka,
                                              f16* __restrict__ ox,
                                              f16* __restrict__ ot,
                                              f16* __restrict__ oa) {
  __shared__ f16 tile[64][65];
  const int tid = threadIdx.x;
  const int t0 = blockIdx.x * 64, s0 = blockIdx.y * 64;
  const float* src = blockIdx.z == 0 ? kx : (blockIdx.z == 1 ? kt : ka);
  f16* dst = blockIdx.z == 0 ? ox : (blockIdx.z == 1 ? ot : oa);
  const int c4 = tid & 15, r0 = tid >> 4;
#pragma unroll
  for (int rr = 0; rr < 64; rr += 16) {
    const float4 v = *(const float4*)(src + (size_t)(t0 + rr + r0) * Tc + s0 + c4 * 4);
    tile[rr + r0][c4 * 4 + 0] = (f16)v.x;
    tile[rr + r0][c4 * 4 + 1] = (f16)v.y;
    tile[rr + r0][c4 * 4 + 2] = (f16)v.z;
    tile[rr + r0][c4 * 4 + 3] = (f16)v.w;
  }
  __syncthreads();
  const int tc = tid & 7, sr = tid >> 3;
#pragma unroll
  for (int sp = 0; sp < 64; sp += 32) {
    const int s = sp + sr;
    f16x8 o;
#pragma unroll
    for (int j = 0; j < 8; ++j) o[j] = tile[tc * 8 + j][s];
    *(f16x8*)(dst + (size_t)(s0 + s) * Tc + t0 + tc * 8) = o;
  }
}

// ---------- 256x256 GEMM, 8-phase schedule, 16x16x32 MFMA (best: R15, 516us) ----------
// BK=64, 2 double-buffered K-tiles; A/B split into 128-row halves (16 KiB).
// Session plateau note: 10 structural variants (pipeline depth, fences, barrier
// density, read-ahead, 8-phase counted-vmcnt, MFMA shape, 2-blocks/CU, L2
// supertile, drain removal, B-direct-to-reg) all land at 147-152us per GEMM
// (~40% MfmaUtil); this configuration is the measured best.
template <int MODE>
__global__ __launch_bounds__(512, 2) void gemm_k(const f16* __restrict__ A,
                                                 const f16* __restrict__ Bm,
                                                 void* __restrict__ Cout,
                                                 const f16* __restrict__ Gprev,
                                                 const float* __restrict__ bias,
                                                 const float* __restrict__ lambd,
                                                 float* __restrict__ psums) {
  extern __shared__ char smem[];
  constexpr int BK = 64, NT = Tc / BK;            // 32 K-tiles
  const int tid = threadIdx.x;
  const int lane = tid & 63, w = tid >> 6;
  const int wr = w >> 2, wc = w & 3;              // 2 x 4 wave grid
  const int l15 = lane & 15, kg = lane >> 4;

  // grid: 512 blocks, XCD-bijective swizzle (512 % 8 == 0)
  int id = (int)blockIdx.x;
  id = (id & 7) * ((int)gridDim.x >> 3) + (id >> 3);
  int b, m0, n0;
  if constexpr (MODE == 2) {
    b = id >> 4; m0 = ((id >> 1) & 7) * 256; n0 = (id & 1) * 256;
  } else {
    b = 0; m0 = (id >> 3) * 256; n0 = (id & 7) * 256;
  }

  const size_t K = Tc;
  const size_t HT = (size_t)Hc * Tc;
  const f16* Ag = A + (size_t)m0 * K;
  const f16* Bg = Bm + (MODE == 2 ? (size_t)b * HT : (size_t)0) + (size_t)n0 * K;

  // staging source (proven swizzle pair): wave w stages rows w*16..w*16+15 per gload
  const int srow = w * 16 + (lane >> 2);
  const int cswz = ((lane & 3) ^ ((lane >> 3) & 3)) * 8;
  const f16* gAs = Ag + (size_t)srow * K + cswz;
  const f16* gBs = Bg + (size_t)srow * K + cswz;
  char* stW = smem + w * 1024;

#define STG(op, h, ktile, d, g)                                                        \
  gload_lds16(((op) ? gBs : gAs) + (size_t)(h) * 128 * Tc + (size_t)(ktile) * BK + (g) * 32, \
              stW + (d) * 65536 + (op) * 32768 + (h) * 16384 + (g) * 8192)
#define STGH(op, h, ktile, d) do { STG(op, h, ktile, d, 0); STG(op, h, ktile, d, 1); } while (0)

  // fragment read bases (proven zero-conflict): + s*8192 + mi(nj)*1024
  const int chunk16 = (kg ^ ((l15 >> 1) & 3)) * 16;
  const char* pA0 = smem + wr * 16384 + l15 * 64 + chunk16;
  const char* pA1 = pA0 + 65536;
  const char* pB0 = smem + 32768 + (wc >> 1) * 16384 + ((wc & 1) * 64 + l15) * 64 + chunk16;
  const char* pB1 = pB0 + 65536;

  f32x4 acc[8][4];
#pragma unroll
  for (int i = 0; i < 8; ++i)
#pragma unroll
    for (int j = 0; j < 4; ++j) acc[i][j] = {0.f, 0.f, 0.f, 0.f};

  f16x8 b00, b01, b10, b11, b20, b21, b30, b31;  // bf[nj][s]
  f16x8 alo0, alo1, ahi0, ahi1;                  // current phase A frags

#define RD_B(P) do {                                     \
    b00 = *(const f16x8*)((P));                          \
    b01 = *(const f16x8*)((P) + 8192);                   \
    b10 = *(const f16x8*)((P) + 1024);                   \
    b11 = *(const f16x8*)((P) + 8192 + 1024);            \
    b20 = *(const f16x8*)((P) + 2048);                   \
    b21 = *(const f16x8*)((P) + 8192 + 2048);            \
    b30 = *(const f16x8*)((P) + 3072);                   \
    b31 = *(const f16x8*)((P) + 8192 + 3072); } while (0)

#define RD_A(P, MI2) do {                                \
    alo0 = *(const f16x8*)((P) + (MI2) * 1024);          \
    alo1 = *(const f16x8*)((P) + 8192 + (MI2) * 1024);   \
    ahi0 = *(const f16x8*)((P) + (MI2 + 1) * 1024);      \
    ahi1 = *(const f16x8*)((P) + 8192 + (MI2 + 1) * 1024); } while (0)

#define MFMA_(a, bq, d) d = __builtin_amdgcn_mfma_f32_16x16x32_f16(a, bq, d, 0, 0, 0)
#define MM8(MI2) do {                                    \
    MFMA_(alo0, b00, acc[MI2][0]); MFMA_(alo0, b10, acc[MI2][1]);         \
    MFMA_(alo0, b20, acc[MI2][2]); MFMA_(alo0, b30, acc[MI2][3]);         \
    MFMA_(ahi0, b00, acc[MI2 + 1][0]); MFMA_(ahi0, b10, acc[MI2 + 1][1]); \
    MFMA_(ahi0, b20, acc[MI2 + 1][2]); MFMA_(ahi0, b30, acc[MI2 + 1][3]); \
    MFMA_(alo1, b01, acc[MI2][0]); MFMA_(alo1, b11, acc[MI2][1]);         \
    MFMA_(alo1, b21, acc[MI2][2]); MFMA_(alo1, b31, acc[MI2][3]);         \
    MFMA_(ahi1, b01, acc[MI2 + 1][0]); MFMA_(ahi1, b11, acc[MI2 + 1][1]); \
    MFMA_(ahi1, b21, acc[MI2 + 1][2]); MFMA_(ahi1, b31, acc[MI2 + 1][3]); } while (0)

#define BAR __builtin_amdgcn_s_barrier()
#define LGKM0 asm volatile("s_waitcnt lgkmcnt(0)")
#define SP1 __builtin_amdgcn_s_setprio(1)
#define SP0 __builtin_amdgcn_s_setprio(0)

  // prologue: tile0 (all 4 halves) -> buf0, B(1) -> buf1; first 8 gloads landed
  STGH(1, 0, 0, 0); STGH(1, 1, 0, 0); STGH(0, 0, 0, 0); STGH(0, 1, 0, 0);
  STGH(1, 0, 1, 1); STGH(1, 1, 1, 1);
  asm volatile("s_waitcnt vmcnt(4)");
  BAR;
  __builtin_amdgcn_sched_barrier(0);

  for (int it = 0; it < NT / 2; ++it) {
    const int u = 2 * it, vT = u + 1;
    const bool full = (it < NT / 2 - 1);
    // ---- L0 (tile u, buf0) ----
    RD_B(pB0); RD_A(pA0, 0);
    STGH(0, 0, vT, 1);                    // Ah0(v) -> buf1 (freed prev L7)
    BAR; LGKM0; SP1; MM8(0); SP0; BAR;
    // ---- L1 ----
    RD_A(pA0, 2);
    STGH(0, 1, vT, 1);                    // Ah1(v) -> buf1
    if (full) STGH(1, 0, u + 2, 0);       // Bh0(u+2) -> buf0 (B freed after L0)
    BAR; LGKM0; SP1; MM8(2); SP0; BAR;
    // ---- L2 ----
    RD_A(pA0, 4);
    if (full) STGH(1, 1, u + 2, 0);
    BAR; LGKM0; SP1; MM8(4); SP0; BAR;
    // ---- L3 ----
    RD_A(pA0, 6);
    BAR; LGKM0; SP1; MM8(6); SP0;
    if (full) { asm volatile("s_waitcnt vmcnt(4)"); }  // A(v),B(v) landed
    else      { asm volatile("s_waitcnt vmcnt(0)"); }
    BAR;
    __builtin_amdgcn_sched_barrier(0);
    // ---- L4 (tile v, buf1) ----
    RD_B(pB1); RD_A(pA1, 0);
    if (full) STGH(0, 0, u + 2, 0);       // Ah0(u+2) -> buf0 (A freed after L3)
    BAR; LGKM0; SP1; MM8(0); SP0; BAR;
    // ---- L5 ----
    RD_A(pA1, 2);
    if (full) { STGH(0, 1, u + 2, 0); STGH(1, 0, vT + 2, 1); }
    BAR; LGKM0; SP1; MM8(2); SP0; BAR;
    // ---- L6 ----
    RD_A(pA1, 4);
    if (full) STGH(1, 1, vT + 2, 1);
    BAR; LGKM0; SP1; MM8(4); SP0; BAR;
    // ---- L7 ----
    RD_A(pA1, 6);
    BAR; LGKM0; SP1; MM8(6); SP0;
    if (full) { asm volatile("s_waitcnt vmcnt(4)"); }  // A(u+2),B(u+2) landed
    else      { asm volatile("s_waitcnt vmcnt(0)"); }
    BAR;
    __builtin_amdgcn_sched_barrier(0);
  }

  // ---- epilogue (hardware-exp transcendentals) ----
  float psum[4] = {0.f, 0.f, 0.f, 0.f};
#pragma unroll
  for (int i = 0; i < 8; ++i) {
#pragma unroll
    for (int r = 0; r < 4; ++r) {
      const int gr = m0 + wr * 128 + i * 16 + kg * 4 + r;
#pragma unroll
      for (int j = 0; j < 4; ++j) {
        const int gc = n0 + wc * 64 + j * 16 + l15;
        const float v = acc[i][j][r];
        if constexpr (MODE == 0) {
          f16* C = (f16*)Cout;
          C[(size_t)gr * Tc + gc] = (f16)fast_tanh(v + bias[gc]);
        } else if constexpr (MODE == 1) {
          f16* C = (f16*)Cout;
          const size_t idx = (size_t)gr * Tc + gc;
          const float g = (float)Gprev[idx];
          const float lam = lambd[gr & 511];
          C[idx] = (f16)(lam * g + (1.f - lam) * fast_tanh(v + bias[gc]));
        } else {
          // no-max softmax numerator: logits O(1); shift-invariant vs reference.
          f16* Es = (f16*)Cout;
          const float e = fast_exp(v);
          Es[((size_t)b * Tc + gr) * Hc + gc] = (f16)e;
          psum[j] += e;
        }
      }
    }
  }
  if constexpr (MODE == 2) {
    float* ps = (float*)smem;
    __syncthreads();
#pragma unroll
    for (int j = 0; j < 4; ++j)
      ps[(wr * 4 + kg) * 256 + (wc * 64 + j * 16 + l15)] = psum[j];
    __syncthreads();
    if (tid < 256) {
      float s = 0.f;
#pragma unroll
      for (int p = 0; p < 8; ++p) s += ps[p * 256 + tid];
      psums[((size_t)b * 8 + (m0 >> 8)) * Hc + n0 + tid] = s;
    }
  }
}

// ---------- normalize: out[b][s'][h] = Es[b][s'][h] / sum_p psums[b][p][h] ----------
__global__ __launch_bounds__(1024) void norm_k(const f16* __restrict__ Es,
                                               const float* __restrict__ psums,
                                               float* __restrict__ out) {
  __shared__ float inv[512];
  const int tid = threadIdx.x;
  const int b = blockIdx.x >> 4, sseg = blockIdx.x & 15;
  if (tid < 512) {
    float s = 0.f;
    const float* P = psums + (size_t)b * 8 * Hc + tid;
#pragma unroll
    for (int p = 0; p < 8; ++p) s += P[p * Hc];
    inv[tid] = 1.f / s;
  }
  __syncthreads();
  const int hg = (tid & 63) * 8;
  const int so = tid >> 6;
  float iv[8];
#pragma unroll
  for (int j = 0; j < 8; ++j) iv[j] = inv[hg + j];
  const size_t base = ((size_t)b * Tc + sseg * 128) * Hc;
  for (int r = so; r < 128; r += 16) {
    const size_t idx = base + (size_t)r * Hc + hg;
    const f16x8 e = *(const f16x8*)(Es + idx);
    float4 o0, o1;
    o0.x = (float)e[0] * iv[0]; o0.y = (float)e[1] * iv[1];
    o0.z = (float)e[2] * iv[2]; o0.w = (float)e[3] * iv[3];
    o1.x = (float)e[4] * iv[4]; o1.y = (float)e[5] * iv[5];
    o1.z = (float)e[6] * iv[6]; o1.w = (float)e[7] * iv[7];
    *(float4*)(out + idx) = o0;
    *(float4*)(out + idx + 4) = o1;
  }
}

extern "C" void kernel_launch(void* const* d_in, const int* in_sizes, int n_in,
                              void* d_out, int out_size, void* d_ws, size_t ws_size,
                              hipStream_t stream) {
  const float* x  = (const float*)d_in[0];
  const float* tt = (const float*)d_in[1];
  const float* kx = (const float*)d_in[2];
  const float* kt = (const float*)d_in[3];
  const float* ka = (const float*)d_in[4];
  const float* bx = (const float*)d_in[5];
  const float* bt = (const float*)d_in[6];
  const float* lm = (const float*)d_in[7];
  float* out = (float*)d_out;

  const size_t NBHT = (size_t)Bc * Hc * Tc;  // 33,554,432 elements

  // d_out doubles as scratch for the f16-transposed inputs until norm_k overwrites it
  f16* XhT = (f16*)d_out;
  f16* ThT = XhT + NBHT;

  // workspace: Gt(64MiB) Dt(64MiB) KxT(8) KtT(8) KaT(8)
  f16* Gt  = (f16*)d_ws;
  f16* Dt  = Gt + NBHT;
  f16* KxT = Dt + NBHT;
  f16* KtT = KxT + (size_t)Tc * Tc;
  f16* KaT = KtT + (size_t)Tc * Tc;
  float* Ps = (float*)KxT;   // psums reuses KxT (dead after gemm_k<0>)
  f16* Es = Gt;              // exp numerators reuse Gt (dead after gemm_k<1>)

  constexpr int LDS_BYTES = 131072;  // 2 bufs x (A 32K + B 32K)
  (void)hipFuncSetAttribute(reinterpret_cast<const void*>(gemm_k<0>),
                            hipFuncAttributeMaxDynamicSharedMemorySize, LDS_BYTES);
  (void)hipFuncSetAttribute(reinterpret_cast<const void*>(gemm_k<1>),
                            hipFuncAttributeMaxDynamicSharedMemorySize, LDS_BYTES);
  (void)hipFuncSetAttribute(reinterpret_cast<const void*>(gemm_k<2>),
                            hipFuncAttributeMaxDynamicSharedMemorySize, LDS_BYTES);

  cvt_bth<<<dim3(Tc / 64, Hc / 64, Bc * 2), 256, 0, stream>>>(x, tt, XhT, ThT);
  cvt_tt<<<dim3(Tc / 64, Tc / 64, 3), 256, 0, stream>>>(kx, kt, ka, KxT, KtT, KaT);
  gemm_k<0><<<512, 512, LDS_BYTES, stream>>>(XhT, KxT, Gt, nullptr, bx, nullptr, nullptr);
  gemm_k<1><<<512, 512, LDS_BYTES, stream>>>(ThT, KtT, Dt, Gt, bt, lm, nullptr);
  gemm_k<2><<<512, 512, LDS_BYTES, stream>>>(KaT, Dt, Es, nullptr, nullptr, nullptr, Ps);
  norm_k<<<dim3(Bc * 16), 1024, 0, stream>>>(Es, Ps, out);
}